// Round 12
// baseline (96.420 us; speedup 1.0000x reference)
//
#include <hip/hip_runtime.h>
#include <math.h>

#define B_ 8
#define N_ 2048
#define H_ 256

// One-shot: W1T[k][o] = W1[o][k] (f32, 256 KB in d_ws) -> unit-stride lane
// reads in s_kernel.
__global__ __launch_bounds__(256)
void transpose_w1(const float* __restrict__ W1, float* __restrict__ W1T) {
    W1T[(size_t)blockIdx.x * H_ + threadIdx.x] =
        W1[(size_t)threadIdx.x * H_ + blockIdx.x];
}

// Kernel A: s[m] = sum_o w2[o] * silu( dot(h[m,:], W1[o,:]) + b1[o] ), f64.
// No LDS, no barriers. Block = 4 waves; wave owns 8 rows x ALL 256 o;
// lane owns 4 o's -> acc[4][8] = 64 VGPR. cvt_f64_f32 tax = 1/O + 1/R =
// 37.5% of FMA count (round 11's R=4 was 50%). h rows wave-uniform ->
// scalar cache (s_load), 4-k chunks ping-ponged in SGPRs (8r x 4k = 32);
// W1T float4 per k, 4-k ping-pong in VGPRs (~512-cy window covers L2).
// waves_per_eu(2,4) keeps the allocator off the 52-VGPR spill regime.
__global__ __launch_bounds__(256)
__attribute__((amdgpu_waves_per_eu(2, 4)))
void s_kernel(const float* __restrict__ hp, const float* __restrict__ W1T,
              const float* __restrict__ b1, const float* __restrict__ w2,
              double* __restrict__ s_out) {
    const int t = threadIdx.x;
    const int lane = t & 63;
    const int wave = __builtin_amdgcn_readfirstlane(t >> 6);
    const int m0 = blockIdx.x * 32 + wave * 8;   // this wave's 8 rows
    const int o0 = lane * 4;                     // this lane's 4 o's

    const float* hr = hp + (size_t)m0 * H_;      // uniform: rows at +r*H_
    const float* wp = W1T + o0;                  // k-row at wp + k*H_

    double acc[4][8];                            // [o_j][row_r]
    #pragma unroll
    for (int j = 0; j < 4; ++j)
        #pragma unroll
        for (int r = 0; r < 8; ++r) acc[j][r] = 0.0;

    float4 wA[4], wB[4];      // W1T chunk: 4 k x lane's 4 o's (VGPR)
    float hA[32], hB[32];     // h chunk: 8 rows x 4 k, wave-uniform (SGPR)

    #define LOADW(dst, kcv)                                                   \
        do {                                                                  \
            _Pragma("unroll")                                                 \
            for (int kk = 0; kk < 4; ++kk)                                    \
                dst[kk] = *reinterpret_cast<const float4*>(                   \
                    wp + (size_t)((kcv) + kk) * H_);                          \
        } while (0)

    #define LOADH(dst, kcv)                                                   \
        do {                                                                  \
            _Pragma("unroll")                                                 \
            for (int r = 0; r < 8; ++r)                                       \
                _Pragma("unroll")                                             \
                for (int kk = 0; kk < 4; ++kk)                                \
                    dst[r * 4 + kk] = hr[r * H_ + (kcv) + kk];                \
        } while (0)

    // Per k: 32 FMAs (4 o x 8 rows), 8 h-cvt + 4 w-cvt shared.
    #define COMPUTE(wv, hbuf)                                                 \
        do {                                                                  \
            _Pragma("unroll")                                                 \
            for (int kk = 0; kk < 4; ++kk) {                                  \
                const double a0 = (double)wv[kk].x;                           \
                const double a1 = (double)wv[kk].y;                           \
                const double a2 = (double)wv[kk].z;                           \
                const double a3 = (double)wv[kk].w;                           \
                _Pragma("unroll")                                             \
                for (int r = 0; r < 8; ++r) {                                 \
                    const double hv = (double)hbuf[r * 4 + kk];               \
                    acc[0][r] = fma(a0, hv, acc[0][r]);                       \
                    acc[1][r] = fma(a1, hv, acc[1][r]);                       \
                    acc[2][r] = fma(a2, hv, acc[2][r]);                       \
                    acc[3][r] = fma(a3, hv, acc[3][r]);                       \
                }                                                             \
            }                                                                 \
        } while (0)

    LOADW(wA, 0);
    LOADH(hA, 0);
    for (int kc = 0; kc < H_; kc += 8) {
        LOADW(wB, kc + 4);                   // prefetch next chunk
        LOADH(hB, kc + 4);
        COMPUTE(wA, hA);                     // 128 FMA (~512 cy) window
        if (kc + 8 < H_) {
            LOADW(wA, kc + 8);
            LOADH(hA, kc + 8);
        }
        COMPUTE(wB, hB);
    }
    #undef LOADW
    #undef LOADH
    #undef COMPUTE

    // Epilogue: bias + silu + w2-dot over this lane's 4 o's.
    const float4 b1v = *reinterpret_cast<const float4*>(b1 + o0);
    const float4 w2v = *reinterpret_cast<const float4*>(w2 + o0);
    double psum[8] = {0.0, 0.0, 0.0, 0.0, 0.0, 0.0, 0.0, 0.0};
    #define EPI(j, bc, wc)                                                    \
        do {                                                                  \
            const double bb = (double)bc, ww = (double)wc;                    \
            _Pragma("unroll")                                                 \
            for (int r = 0; r < 8; ++r) {                                     \
                const double u = acc[j][r] + bb;                              \
                psum[r] += ww * (u / (1.0 + exp(-u)));                        \
            }                                                                 \
        } while (0)
    EPI(0, b1v.x, w2v.x);
    EPI(1, b1v.y, w2v.y);
    EPI(2, b1v.z, w2v.z);
    EPI(3, b1v.w, w2v.w);
    #undef EPI

    // Full-wave reduce (64 lanes cover all 256 o's); lane 0 writes s.
    #pragma unroll
    for (int r = 0; r < 8; ++r) {
        double v = psum[r];
        v += __shfl_xor(v, 1, 64);
        v += __shfl_xor(v, 2, 64);
        v += __shfl_xor(v, 4, 64);
        v += __shfl_xor(v, 8, 64);
        v += __shfl_xor(v, 16, 64);
        v += __shfl_xor(v, 32, 64);
        if (lane == 0) s_out[m0 + r] = v;
    }
}

// Kernel B: out[b,i,j] = (int32)trunc( (s[b,i] - s[b,j]) + b2 )
__global__ __launch_bounds__(256)
void pair_kernel(const double* __restrict__ s, const float* __restrict__ b2p,
                 int* __restrict__ out) {
    const double b2 = (double)b2p[0];
    const unsigned total4 = (unsigned)(B_) * (unsigned)(N_) * (unsigned)(N_) / 4u;
    const unsigned stride = gridDim.x * blockDim.x;
    for (unsigned idx = blockIdx.x * blockDim.x + threadIdx.x; idx < total4;
         idx += stride) {
        const unsigned base = idx * 4u;                 // element index, %4==0
        const unsigned bi  = base >> 22;                // / (N*N), N*N = 2^22
        const unsigned rem = base & ((1u << 22) - 1u);
        const unsigned i   = rem >> 11;                 // / N
        const unsigned j   = rem & (N_ - 1u);
        const double si = s[bi * N_ + i];
        const double* sp = s + bi * N_ + j;             // 32B aligned (j%4==0)
        const double sj0 = sp[0], sj1 = sp[1], sj2 = sp[2], sj3 = sp[3];
        int4 o;
        o.x = (int)trunc((si - sj0) + b2);
        o.y = (int)trunc((si - sj1) + b2);
        o.z = (int)trunc((si - sj2) + b2);
        o.w = (int)trunc((si - sj3) + b2);
        *reinterpret_cast<int4*>(out + base) = o;
    }
}

extern "C" void kernel_launch(void* const* d_in, const int* in_sizes, int n_in,
                              void* d_out, int out_size, void* d_ws, size_t ws_size,
                              hipStream_t stream) {
    const float* hp = (const float*)d_in[0];
    // d_in[1] = node_mask (unused), d_in[2] = n_nodes (unused)
    const float* W1 = (const float*)d_in[3];
    const float* b1 = (const float*)d_in[4];
    const float* w2 = (const float*)d_in[5];
    const float* b2 = (const float*)d_in[6];

    float* W1T = (float*)d_ws;                                     // 256 KB
    double* s  = (double*)((char*)d_ws + H_ * H_ * sizeof(float)); // 128 KB
    int* out = (int*)d_out;

    transpose_w1<<<H_, H_, 0, stream>>>(W1, W1T);
    s_kernel<<<(B_ * N_) / 32, 256, 0, stream>>>(hp, W1T, b1, w2, s);
    pair_kernel<<<2048, 256, 0, stream>>>(s, b2, out);
}